// Round 1
// baseline (440.468 us; speedup 1.0000x reference)
//
#include <hip/hip_runtime.h>
#include <math.h>

// Problem constants (from reference setup_inputs)
#define BB 4
#define NN 1000
#define CC 2048
#define TINV (1.0f / 0.07f)

// Workspace layout (floats):
//   [0, NORM_F)                : normalized features, fp32, B*N*C
//   [NORM_F, NORM_F+SIM_F)     : sim matrix, fp32, B*N*N
//   [NORM_F+SIM_F, +2*BB)      : per-sample accumulators {loss_sum, pos_sum} x B
#define NORM_F ((size_t)BB * NN * CC)
#define SIM_F  ((size_t)BB * NN * NN)

// ---------------------------------------------------------------------------
// Block-wide sum for blockDim.x == 256 (4 waves of 64)
__device__ __forceinline__ float blk_sum(float v, volatile float* lds) {
    int lane = threadIdx.x & 63;
    int wid  = threadIdx.x >> 6;
#pragma unroll
    for (int off = 32; off; off >>= 1) v += __shfl_down(v, off);
    __syncthreads();                 // protect lds reuse across calls
    if (lane == 0) lds[wid] = v;
    __syncthreads();
    return lds[0] + lds[1] + lds[2] + lds[3];
}

// ---------------------------------------------------------------------------
// K1: L2-normalize each row of f (matches F.normalize: norm = max(||f||,1e-12))
__global__ __launch_bounds__(256) void norm_kernel(const float* __restrict__ f,
                                                   float* __restrict__ out) {
    __shared__ float lds[4];
    __shared__ float scale_s;
    const int row = blockIdx.x;                 // b*NN + i
    const float* src = f + (size_t)row * CC;
    float* dst = out + (size_t)row * CC;

    float ss = 0.f;
    for (int k = threadIdx.x; k < CC / 4; k += 256) {
        float4 v = ((const float4*)src)[k];
        ss += v.x * v.x + v.y * v.y + v.z * v.z + v.w * v.w;
    }
    float tot = blk_sum(ss, lds);
    if (threadIdx.x == 0) {
        float nrm = fmaxf(sqrtf(tot), 1e-12f);
        scale_s = 1.0f / nrm;
    }
    __syncthreads();
    const float sc = scale_s;
    for (int k = threadIdx.x; k < CC / 4; k += 256) {
        float4 v = ((const float4*)src)[k];
        v.x *= sc; v.y *= sc; v.z *= sc; v.w *= sc;
        ((float4*)dst)[k] = v;
    }
}

// ---------------------------------------------------------------------------
// K2: sim[b] = (fn[b] * fn[b]^T) * (1/T).  fp32 tiled GEMM.
// 64x64 tile, BK=32, 256 threads, 4x4 micro-tile per thread.
// LDS stored K-major [BK][64+4] so fragment reads are aligned ds_read_b128.
__global__ __launch_bounds__(256) void simgemm_kernel(const float* __restrict__ fn,
                                                      float* __restrict__ sim) {
    __shared__ float As[32][68];
    __shared__ float Bs[32][68];

    const int b  = blockIdx.z;
    const int tI = blockIdx.y * 64;
    const int tJ = blockIdx.x * 64;
    const float* A = fn + (size_t)b * NN * CC;
    float* S = sim + (size_t)b * NN * NN;

    const int tid = threadIdx.x;
    const int tr = (tid >> 4) * 4;   // acc row offset 0..60
    const int tc = (tid & 15) * 4;   // acc col offset 0..60

    // loader: 64 rows x 32 cols = 512 float4 per matrix; 2 per thread
    const int r0 = tid >> 3;         // 0..31
    const int c0 = (tid & 7) * 4;    // 0..28

    float acc[4][4] = {{0.f}};

    for (int k0 = 0; k0 < CC; k0 += 32) {
#pragma unroll
        for (int h = 0; h < 2; ++h) {
            int row = r0 + h * 32;   // 0..63
            int gi = tI + row;
            float4 va = make_float4(0.f, 0.f, 0.f, 0.f);
            if (gi < NN) va = *(const float4*)(A + (size_t)gi * CC + k0 + c0);
            As[c0 + 0][row] = va.x; As[c0 + 1][row] = va.y;
            As[c0 + 2][row] = va.z; As[c0 + 3][row] = va.w;
            int gj = tJ + row;
            float4 vb = make_float4(0.f, 0.f, 0.f, 0.f);
            if (gj < NN) vb = *(const float4*)(A + (size_t)gj * CC + k0 + c0);
            Bs[c0 + 0][row] = vb.x; Bs[c0 + 1][row] = vb.y;
            Bs[c0 + 2][row] = vb.z; Bs[c0 + 3][row] = vb.w;
        }
        __syncthreads();
#pragma unroll
        for (int kk = 0; kk < 32; ++kk) {
            float4 a  = *(const float4*)&As[kk][tr];
            float4 b4 = *(const float4*)&Bs[kk][tc];
            acc[0][0] += a.x * b4.x; acc[0][1] += a.x * b4.y;
            acc[0][2] += a.x * b4.z; acc[0][3] += a.x * b4.w;
            acc[1][0] += a.y * b4.x; acc[1][1] += a.y * b4.y;
            acc[1][2] += a.y * b4.z; acc[1][3] += a.y * b4.w;
            acc[2][0] += a.z * b4.x; acc[2][1] += a.z * b4.y;
            acc[2][2] += a.z * b4.z; acc[2][3] += a.z * b4.w;
            acc[3][0] += a.w * b4.x; acc[3][1] += a.w * b4.y;
            acc[3][2] += a.w * b4.z; acc[3][3] += a.w * b4.w;
        }
        __syncthreads();
    }

#pragma unroll
    for (int r = 0; r < 4; ++r) {
        int gi = tI + tr + r;
        if (gi >= NN) continue;
#pragma unroll
        for (int c = 0; c < 4; ++c) {
            int gj = tJ + tc + c;
            if (gj < NN) S[(size_t)gi * NN + gj] = acc[r][c] * TINV;
        }
    }
}

// ---------------------------------------------------------------------------
// K3: per-row masked reductions. One block per (b,i).
// Row loss-mat sum = (N - p_i)*log(1+S_i) + sum_{pos j}[log(exp(s)+S_i) - s]
// Diagonal excluded from S_i by masking j==i (NOT by subtracting exp(sim_ii):
// exp(1/0.07)=1.6e6 vs S_i~1e3 would be catastrophic cancellation).
__global__ __launch_bounds__(256) void rowloss_kernel(const float* __restrict__ sim,
                                                      const int* __restrict__ tgt,
                                                      float* __restrict__ acc) {
    __shared__ float lds[4];
    const int b = blockIdx.y;
    const int i = blockIdx.x;
    const float* row = sim + ((size_t)b * NN + i) * NN;
    const int* t = tgt + (size_t)b * NN;
    const int ti = t[i];

    float sneg = 0.f, pcnt = 0.f;
    float posv[4];                      // ceil(1000/256)=4 j's per thread max
    int pn = 0;
    for (int j = threadIdx.x; j < NN; j += 256) {
        if (j == i) continue;
        float s = row[j];
        if (t[j] == ti) { posv[pn++] = s; pcnt += 1.f; }
        else            sneg += __expf(s);
    }
    const float S = blk_sum(sneg, lds);
    const float p = blk_sum(pcnt, lds);
    float term = 0.f;
    for (int k = 0; k < pn; ++k)
        term += __logf(__expf(posv[k]) + S) - posv[k];
    const float tt = blk_sum(term, lds);
    if (threadIdx.x == 0) {
        float total = tt + ((float)NN - p) * __logf(1.f + S);
        atomicAdd(&acc[b * 2 + 0], total);
        atomicAdd(&acc[b * 2 + 1], p);
    }
}

// ---------------------------------------------------------------------------
// K4: combine per-sample losses exactly as the reference does.
__global__ void final_kernel(const float* __restrict__ acc, float* __restrict__ out) {
    float total = 0.f, np = 0.f;
    for (int b = 0; b < BB; ++b) {
        float ps = acc[b * 2 + 1];
        if (ps > 0.f) { total += acc[b * 2 + 0] / (ps + 1e-6f); np += 1.f; }
    }
    out[0] = (np > 0.f) ? 0.1f * total / np : 0.1f * 0.1f;
}

// ---------------------------------------------------------------------------
extern "C" void kernel_launch(void* const* d_in, const int* in_sizes, int n_in,
                              void* d_out, int out_size, void* d_ws, size_t ws_size,
                              hipStream_t stream) {
    const float* feat = (const float*)d_in[0];
    const int*   tgt  = (const int*)d_in[1];   // int inputs arrive as int32
    float* wsf   = (float*)d_ws;
    float* fnorm = wsf;
    float* sim   = wsf + NORM_F;
    float* acc   = wsf + NORM_F + SIM_F;

    hipMemsetAsync(acc, 0, 2 * BB * sizeof(float), stream);

    norm_kernel<<<dim3(BB * NN), 256, 0, stream>>>(feat, fnorm);
    simgemm_kernel<<<dim3(16, 16, BB), 256, 0, stream>>>(fnorm, sim);
    rowloss_kernel<<<dim3(NN, BB), 256, 0, stream>>>(sim, tgt, acc);
    final_kernel<<<1, 1, 0, stream>>>(acc, (float*)d_out);
}

// Round 2
// 225.955 us; speedup vs baseline: 1.9494x; 1.9494x over previous
//
#include <hip/hip_runtime.h>
#include <math.h>

// Problem constants (from reference setup_inputs)
#define BB 4
#define NN 1000
#define NP 1024          // padded N for MFMA tiles
#define CC 2048
#define TINV (1.0f / 0.07f)

// Workspace layout:
//   [0, 16 MB)       : normalized features, bf16, B*NP*CC (rows >= NN zeroed)
//   [16 MB, 32.8 MB) : sim matrix, fp32, B*NP*NP (padded stride)
//   then             : per-sample accumulators {loss_sum, pos_sum} x B
#define FNORM_BYTES ((size_t)BB * NP * CC * 2)
#define SIM_BYTES   ((size_t)BB * NP * NP * 4)

typedef __bf16 bf16x8 __attribute__((ext_vector_type(8)));
typedef float  f32x4  __attribute__((ext_vector_type(4)));

// ---------------------------------------------------------------------------
__device__ __forceinline__ void load_lds16(const void* g, void* l) {
    // async global->LDS, 16B/lane; LDS dest = wave-uniform base + lane*16
    __builtin_amdgcn_global_load_lds(
        (const __attribute__((address_space(1))) unsigned int*)g,
        (__attribute__((address_space(3))) unsigned int*)l, 16, 0, 0);
}

__device__ __forceinline__ float blk_sum(float v, volatile float* lds) {
    int lane = threadIdx.x & 63;
    int wid  = threadIdx.x >> 6;
#pragma unroll
    for (int off = 32; off; off >>= 1) v += __shfl_down(v, off);
    __syncthreads();
    if (lane == 0) lds[wid] = v;
    __syncthreads();
    return lds[0] + lds[1] + lds[2] + lds[3];
}

__device__ __forceinline__ float wave_sum(float v) {
#pragma unroll
    for (int off = 32; off; off >>= 1) v += __shfl_down(v, off);
    return __shfl(v, 0);
}

// ---------------------------------------------------------------------------
// K1: L2-normalize each row, output bf16 into padded [NP x CC] buffer.
// Rows >= NN are zero-filled (so the GEMM needs no bounds checks).
__global__ __launch_bounds__(256) void norm_bf16_kernel(const float* __restrict__ f,
                                                        __bf16* __restrict__ out) {
    __shared__ float lds[4];
    __shared__ float scale_s;
    const int blk = blockIdx.x;              // b*NP + padded row
    const int b = blk >> 10, r = blk & (NP - 1);
    __bf16* dst = out + ((size_t)b * NP + r) * CC;
    const int tid = threadIdx.x;

    if (r >= NN) {                           // zero pad rows: 2048 bf16 = 256 x 16B
        ((uint4*)dst)[tid] = make_uint4(0u, 0u, 0u, 0u);
        return;
    }
    const float* src = f + ((size_t)b * NN + r) * CC;

    float ss = 0.f;
#pragma unroll
    for (int h = 0; h < 2; ++h) {
        float4 v = ((const float4*)src)[tid + h * 256];
        ss += v.x * v.x + v.y * v.y + v.z * v.z + v.w * v.w;
    }
    float tot = blk_sum(ss, lds);
    if (tid == 0) scale_s = 1.0f / fmaxf(sqrtf(tot), 1e-12f);
    __syncthreads();
    const float sc = scale_s;

    float4 v0 = ((const float4*)src)[tid * 2];
    float4 v1 = ((const float4*)src)[tid * 2 + 1];
    bf16x8 o;
    o[0] = (__bf16)(v0.x * sc); o[1] = (__bf16)(v0.y * sc);
    o[2] = (__bf16)(v0.z * sc); o[3] = (__bf16)(v0.w * sc);
    o[4] = (__bf16)(v1.x * sc); o[5] = (__bf16)(v1.y * sc);
    o[6] = (__bf16)(v1.z * sc); o[7] = (__bf16)(v1.w * sc);
    *(bf16x8*)(dst + tid * 8) = o;
}

// ---------------------------------------------------------------------------
// K2: sim[b] = (fn[b] * fn[b]^T) * (1/T), bf16 MFMA.
// 128x128 tile, BK=32, 512 threads (8 waves), each wave computes 64x32
// (4x2 grid of 16x16x32 MFMA). Staging via global_load_lds width=16.
// LDS tiles row-major [128][32] bf16 (no pad — required by global_load_lds
// lane-contiguity); A-frag: lane reads row (l&15), k-chunk (l>>4)*8.
__global__ __launch_bounds__(512) void simgemm_mfma(const __bf16* __restrict__ fn,
                                                    float* __restrict__ sim) {
    __shared__ __bf16 As[128 * 32];
    __shared__ __bf16 Bs[128 * 32];

    const int b  = blockIdx.z;
    const int tI = blockIdx.y * 128;
    const int tJ = blockIdx.x * 128;
    const __bf16* base = fn + (size_t)b * NP * CC;
    float* S = sim + (size_t)b * NP * NP;

    const int tid  = threadIdx.x;
    const int wid  = tid >> 6;       // 0..7
    const int lane = tid & 63;
    const int wm   = wid >> 2;       // 0..1  (M quadrant, 64 rows)
    const int wn   = wid & 3;        // 0..3  (N quadrant, 32 cols)
    const int q    = lane >> 4;      // 0..3
    const int ln   = lane & 15;

    // staging: A = 128 rows x 64B = 8 issues of 1KB; 1 issue/wave (B same)
    const int srow  = wid * 16 + (lane >> 2);       // 0..127
    const int selem = (lane & 3) * 8;               // bf16 elem offset in row
    const __bf16* gA = base + (size_t)(tI + srow) * CC + selem;
    const __bf16* gB = base + (size_t)(tJ + srow) * CC + selem;
    __bf16* lA = As + wid * 512;     // wave-uniform LDS base (lane*16B implicit)
    __bf16* lB = Bs + wid * 512;

    f32x4 acc[4][2] = {};

    for (int k0 = 0; k0 < CC; k0 += 32) {
        load_lds16(gA + k0, lA);
        load_lds16(gB + k0, lB);
        __syncthreads();             // drains vmcnt(0): LDS tiles ready

        bf16x8 af[4], bf[2];
#pragma unroll
        for (int mt = 0; mt < 4; ++mt)
            af[mt] = *(const bf16x8*)&As[(wm * 64 + mt * 16 + ln) * 32 + q * 8];
#pragma unroll
        for (int nt = 0; nt < 2; ++nt)
            bf[nt] = *(const bf16x8*)&Bs[(wn * 32 + nt * 16 + ln) * 32 + q * 8];
#pragma unroll
        for (int mt = 0; mt < 4; ++mt)
#pragma unroll
            for (int nt = 0; nt < 2; ++nt)
                acc[mt][nt] = __builtin_amdgcn_mfma_f32_16x16x32_bf16(
                    af[mt], bf[nt], acc[mt][nt], 0, 0, 0);
        __syncthreads();             // all waves done reading before overwrite
    }

    // C/D layout (m89-verified): col = lane&15, row = (lane>>4)*4 + r
#pragma unroll
    for (int mt = 0; mt < 4; ++mt) {
#pragma unroll
        for (int nt = 0; nt < 2; ++nt) {
            const int col = tJ + wn * 32 + nt * 16 + ln;
#pragma unroll
            for (int r = 0; r < 4; ++r) {
                const int row = tI + wm * 64 + mt * 16 + q * 4 + r;
                S[(size_t)row * NP + col] = acc[mt][nt][r] * TINV;
            }
        }
    }
}

// ---------------------------------------------------------------------------
// K3: per-row masked reductions, one WAVE per row (4 rows/block).
// Row loss-mat sum = (N - p_i)*log(1+S_i) + sum_{pos j}[log(exp(s)+S_i) - s]
// Diagonal excluded by masking j==i (NOT by subtracting exp(sim_ii):
// exp(1/0.07)=1.6e6 vs S_i~1e3 would be catastrophic cancellation).
__global__ __launch_bounds__(256) void rowloss_kernel(const float* __restrict__ sim,
                                                      const int* __restrict__ tgt,
                                                      float* __restrict__ acc) {
    __shared__ int ts[NN];
    const int b = blockIdx.y;
    const int wid = threadIdx.x >> 6, lane = threadIdx.x & 63;
    const int* t = tgt + (size_t)b * NN;
    for (int j = threadIdx.x; j < NN; j += 256) ts[j] = t[j];
    __syncthreads();

    const int i = blockIdx.x * 4 + wid;            // grid.x = 250 -> i < 1000
    const float* row = sim + ((size_t)b * NP + i) * NP;
    const int ti = ts[i];

    float sneg = 0.f, pcnt = 0.f;
    for (int g = lane; g < NN / 4; g += 64) {      // 250 float4 groups
        float4 v = ((const float4*)row)[g];
        const int j = g * 4;
        if (j + 0 != i) { if (ts[j + 0] == ti) pcnt += 1.f; else sneg += __expf(v.x); }
        if (j + 1 != i) { if (ts[j + 1] == ti) pcnt += 1.f; else sneg += __expf(v.y); }
        if (j + 2 != i) { if (ts[j + 2] == ti) pcnt += 1.f; else sneg += __expf(v.z); }
        if (j + 3 != i) { if (ts[j + 3] == ti) pcnt += 1.f; else sneg += __expf(v.w); }
    }
    const float Sv = wave_sum(sneg);
    const float p  = wave_sum(pcnt);

    float term = 0.f;                               // second pass: rows are L2-hot
    for (int g = lane; g < NN / 4; g += 64) {
        float4 v = ((const float4*)row)[g];
        const int j = g * 4;
        if (j + 0 != i && ts[j + 0] == ti) term += __logf(__expf(v.x) + Sv) - v.x;
        if (j + 1 != i && ts[j + 1] == ti) term += __logf(__expf(v.y) + Sv) - v.y;
        if (j + 2 != i && ts[j + 2] == ti) term += __logf(__expf(v.z) + Sv) - v.z;
        if (j + 3 != i && ts[j + 3] == ti) term += __logf(__expf(v.w) + Sv) - v.w;
    }
    const float tt = wave_sum(term);
    if (lane == 0) {
        atomicAdd(&acc[b * 2 + 0], tt + ((float)NN - p) * __logf(1.f + Sv));
        atomicAdd(&acc[b * 2 + 1], p);
    }
}

// ---------------------------------------------------------------------------
// K4: combine per-sample losses exactly as the reference does.
__global__ void final_kernel(const float* __restrict__ acc, float* __restrict__ out) {
    float total = 0.f, np = 0.f;
    for (int b = 0; b < BB; ++b) {
        float ps = acc[b * 2 + 1];
        if (ps > 0.f) { total += acc[b * 2 + 0] / (ps + 1e-6f); np += 1.f; }
    }
    out[0] = (np > 0.f) ? 0.1f * total / np : 0.1f * 0.1f;
}

// ---------------------------------------------------------------------------
extern "C" void kernel_launch(void* const* d_in, const int* in_sizes, int n_in,
                              void* d_out, int out_size, void* d_ws, size_t ws_size,
                              hipStream_t stream) {
    const float* feat = (const float*)d_in[0];
    const int*   tgt  = (const int*)d_in[1];
    __bf16* fnorm = (__bf16*)d_ws;
    float*  sim   = (float*)((char*)d_ws + FNORM_BYTES);
    float*  acc   = (float*)((char*)d_ws + FNORM_BYTES + SIM_BYTES);

    hipMemsetAsync(acc, 0, 2 * BB * sizeof(float), stream);

    norm_bf16_kernel<<<dim3(BB * NP), 256, 0, stream>>>(feat, fnorm);
    simgemm_mfma<<<dim3(NP / 128, NP / 128, BB), 512, 0, stream>>>(fnorm, sim);
    rowloss_kernel<<<dim3(NN / 4, BB), 256, 0, stream>>>(sim, tgt, acc);
    final_kernel<<<1, 1, 0, stream>>>(acc, (float*)d_out);
}

// Round 3
// 130.878 us; speedup vs baseline: 3.3655x; 1.7265x over previous
//
#include <hip/hip_runtime.h>
#include <math.h>

// Problem constants (from reference setup_inputs)
#define BB 4
#define NN 1000
#define NP 1024          // padded N for MFMA tiles
#define CC 2048
#define TINV (1.0f / 0.07f)

// Workspace layout:
//   [0, 16 MB)       : normalized features, bf16, B*NP*CC (rows >= NN zeroed)
//   [16 MB, 32.8 MB) : sim matrix, fp32, B*NP*NP (padded stride)
//   then             : per-row loss sums  rloss[B*NP]
//   then             : per-row pos counts rpos[B*NP]
// No atomics anywhere: R2 showed 8000 same-line device atomicAdds serialize
// at ~14 ns each = the whole 110 us rowloss time.
#define FNORM_BYTES ((size_t)BB * NP * CC * 2)
#define SIM_BYTES   ((size_t)BB * NP * NP * 4)
#define RL_BYTES    ((size_t)BB * NP * 4)

typedef __bf16 bf16x8 __attribute__((ext_vector_type(8)));
typedef float  f32x4  __attribute__((ext_vector_type(4)));

// ---------------------------------------------------------------------------
__device__ __forceinline__ void load_lds16(const void* g, void* l) {
    // async global->LDS, 16B/lane; LDS dest = wave-uniform base + lane*16
    __builtin_amdgcn_global_load_lds(
        (const __attribute__((address_space(1))) unsigned int*)g,
        (__attribute__((address_space(3))) unsigned int*)l, 16, 0, 0);
}

__device__ __forceinline__ float blk_sum(float v, volatile float* lds) {
    int lane = threadIdx.x & 63;
    int wid  = threadIdx.x >> 6;
#pragma unroll
    for (int off = 32; off; off >>= 1) v += __shfl_down(v, off);
    __syncthreads();
    if (lane == 0) lds[wid] = v;
    __syncthreads();
    return lds[0] + lds[1] + lds[2] + lds[3];
}

__device__ __forceinline__ float wave_sum(float v) {
#pragma unroll
    for (int off = 32; off; off >>= 1) v += __shfl_down(v, off);
    return __shfl(v, 0);
}

// ---------------------------------------------------------------------------
// K1: L2-normalize each row, output bf16 into padded [NP x CC] buffer.
// Rows >= NN are zero-filled (so the GEMM needs no bounds checks).
__global__ __launch_bounds__(256) void norm_bf16_kernel(const float* __restrict__ f,
                                                        __bf16* __restrict__ out) {
    __shared__ float lds[4];
    __shared__ float scale_s;
    const int blk = blockIdx.x;              // b*NP + padded row
    const int b = blk >> 10, r = blk & (NP - 1);
    __bf16* dst = out + ((size_t)b * NP + r) * CC;
    const int tid = threadIdx.x;

    if (r >= NN) {                           // zero pad rows: 2048 bf16 = 256 x 16B
        ((uint4*)dst)[tid] = make_uint4(0u, 0u, 0u, 0u);
        return;
    }
    const float* src = f + ((size_t)b * NN + r) * CC;

    float ss = 0.f;
#pragma unroll
    for (int h = 0; h < 2; ++h) {
        float4 v = ((const float4*)src)[tid + h * 256];
        ss += v.x * v.x + v.y * v.y + v.z * v.z + v.w * v.w;
    }
    float tot = blk_sum(ss, lds);
    if (tid == 0) scale_s = 1.0f / fmaxf(sqrtf(tot), 1e-12f);
    __syncthreads();
    const float sc = scale_s;

    float4 v0 = ((const float4*)src)[tid * 2];
    float4 v1 = ((const float4*)src)[tid * 2 + 1];
    bf16x8 o;
    o[0] = (__bf16)(v0.x * sc); o[1] = (__bf16)(v0.y * sc);
    o[2] = (__bf16)(v0.z * sc); o[3] = (__bf16)(v0.w * sc);
    o[4] = (__bf16)(v1.x * sc); o[5] = (__bf16)(v1.y * sc);
    o[6] = (__bf16)(v1.z * sc); o[7] = (__bf16)(v1.w * sc);
    *(bf16x8*)(dst + tid * 8) = o;
}

// ---------------------------------------------------------------------------
// K2: sim[b] = (fn[b] * fn[b]^T) * (1/T), bf16 MFMA.
// 128x128 tile, BK=32, 512 threads (8 waves), each wave computes 64x32
// (4x2 grid of 16x16x32 MFMA). Staging via global_load_lds width=16.
__global__ __launch_bounds__(512) void simgemm_mfma(const __bf16* __restrict__ fn,
                                                    float* __restrict__ sim) {
    __shared__ __bf16 As[128 * 32];
    __shared__ __bf16 Bs[128 * 32];

    const int b  = blockIdx.z;
    const int tI = blockIdx.y * 128;
    const int tJ = blockIdx.x * 128;
    const __bf16* base = fn + (size_t)b * NP * CC;
    float* S = sim + (size_t)b * NP * NP;

    const int tid  = threadIdx.x;
    const int wid  = tid >> 6;       // 0..7
    const int lane = tid & 63;
    const int wm   = wid >> 2;       // 0..1  (M quadrant, 64 rows)
    const int wn   = wid & 3;        // 0..3  (N quadrant, 32 cols)
    const int q    = lane >> 4;      // 0..3
    const int ln   = lane & 15;

    const int srow  = wid * 16 + (lane >> 2);       // 0..127
    const int selem = (lane & 3) * 8;               // bf16 elem offset in row
    const __bf16* gA = base + (size_t)(tI + srow) * CC + selem;
    const __bf16* gB = base + (size_t)(tJ + srow) * CC + selem;
    __bf16* lA = As + wid * 512;     // wave-uniform LDS base (lane*16B implicit)
    __bf16* lB = Bs + wid * 512;

    f32x4 acc[4][2] = {};

    for (int k0 = 0; k0 < CC; k0 += 32) {
        load_lds16(gA + k0, lA);
        load_lds16(gB + k0, lB);
        __syncthreads();             // drains vmcnt(0): LDS tiles ready

        bf16x8 af[4], bf[2];
#pragma unroll
        for (int mt = 0; mt < 4; ++mt)
            af[mt] = *(const bf16x8*)&As[(wm * 64 + mt * 16 + ln) * 32 + q * 8];
#pragma unroll
        for (int nt = 0; nt < 2; ++nt)
            bf[nt] = *(const bf16x8*)&Bs[(wn * 32 + nt * 16 + ln) * 32 + q * 8];
#pragma unroll
        for (int mt = 0; mt < 4; ++mt)
#pragma unroll
            for (int nt = 0; nt < 2; ++nt)
                acc[mt][nt] = __builtin_amdgcn_mfma_f32_16x16x32_bf16(
                    af[mt], bf[nt], acc[mt][nt], 0, 0, 0);
        __syncthreads();             // all waves done reading before overwrite
    }

    // C/D layout (m89-verified): col = lane&15, row = (lane>>4)*4 + r
#pragma unroll
    for (int mt = 0; mt < 4; ++mt) {
#pragma unroll
        for (int nt = 0; nt < 2; ++nt) {
            const int col = tJ + wn * 32 + nt * 16 + ln;
#pragma unroll
            for (int r = 0; r < 4; ++r) {
                const int row = tI + wm * 64 + mt * 16 + q * 4 + r;
                S[(size_t)row * NP + col] = acc[mt][nt][r] * TINV;
            }
        }
    }
}

// ---------------------------------------------------------------------------
// K3: per-row masked reductions, one WAVE per row (4 rows/block).
// Row loss-mat sum = (N - p_i)*log(1+S_i) + sum_{pos j}[log(exp(s)+S_i) - s]
// Diagonal excluded by masking j==i (NOT by subtracting exp(sim_ii):
// exp(1/0.07)=1.6e6 vs S_i~1e3 would be catastrophic cancellation).
// NO atomics: plain per-row stores; final_kernel reduces.
__global__ __launch_bounds__(256) void rowloss_kernel(const float* __restrict__ sim,
                                                      const int* __restrict__ tgt,
                                                      float* __restrict__ rloss,
                                                      float* __restrict__ rpos) {
    __shared__ int ts[NN];
    const int b = blockIdx.y;
    const int wid = threadIdx.x >> 6, lane = threadIdx.x & 63;
    const int* t = tgt + (size_t)b * NN;
    for (int j = threadIdx.x; j < NN; j += 256) ts[j] = t[j];
    __syncthreads();

    const int i = blockIdx.x * 4 + wid;            // grid.x = 250 -> i < 1000
    const float* row = sim + ((size_t)b * NP + i) * NP;
    const int ti = ts[i];

    float sneg = 0.f, pcnt = 0.f;
    for (int g = lane; g < NN / 4; g += 64) {      // 250 float4 groups
        float4 v = ((const float4*)row)[g];
        int4 tj = *(const int4*)&ts[g * 4];        // 16B-aligned LDS read
        const int j = g * 4;
        if (j + 0 != i) { if (tj.x == ti) pcnt += 1.f; else sneg += __expf(v.x); }
        if (j + 1 != i) { if (tj.y == ti) pcnt += 1.f; else sneg += __expf(v.y); }
        if (j + 2 != i) { if (tj.z == ti) pcnt += 1.f; else sneg += __expf(v.z); }
        if (j + 3 != i) { if (tj.w == ti) pcnt += 1.f; else sneg += __expf(v.w); }
    }
    const float Sv = wave_sum(sneg);
    const float p  = wave_sum(pcnt);

    float term = 0.f;                               // second pass: rows are L2-hot
    for (int g = lane; g < NN / 4; g += 64) {
        float4 v = ((const float4*)row)[g];
        int4 tj = *(const int4*)&ts[g * 4];
        const int j = g * 4;
        if (j + 0 != i && tj.x == ti) term += __logf(__expf(v.x) + Sv) - v.x;
        if (j + 1 != i && tj.y == ti) term += __logf(__expf(v.y) + Sv) - v.y;
        if (j + 2 != i && tj.z == ti) term += __logf(__expf(v.z) + Sv) - v.z;
        if (j + 3 != i && tj.w == ti) term += __logf(__expf(v.w) + Sv) - v.w;
    }
    const float tt = wave_sum(term);
    if (lane == 0) {
        rloss[b * NP + i] = tt + ((float)NN - p) * __logf(1.f + Sv);
        rpos [b * NP + i] = p;
    }
}

// ---------------------------------------------------------------------------
// K4: reduce per-row partials and combine exactly as the reference does.
__global__ __launch_bounds__(256) void final_kernel(const float* __restrict__ rloss,
                                                    const float* __restrict__ rpos,
                                                    float* __restrict__ out) {
    __shared__ float lds[4];
    float total = 0.f, np = 0.f;
    for (int b = 0; b < BB; ++b) {
        float l = 0.f, p = 0.f;
        for (int i = threadIdx.x; i < NN; i += 256) {
            l += rloss[b * NP + i];
            p += rpos [b * NP + i];
        }
        float ls = blk_sum(l, lds);
        float ps = blk_sum(p, lds);
        if (ps > 0.f) { total += ls / (ps + 1e-6f); np += 1.f; }
    }
    if (threadIdx.x == 0)
        out[0] = (np > 0.f) ? 0.1f * total / np : 0.1f * 0.1f;
}

// ---------------------------------------------------------------------------
extern "C" void kernel_launch(void* const* d_in, const int* in_sizes, int n_in,
                              void* d_out, int out_size, void* d_ws, size_t ws_size,
                              hipStream_t stream) {
    const float* feat = (const float*)d_in[0];
    const int*   tgt  = (const int*)d_in[1];
    __bf16* fnorm = (__bf16*)d_ws;
    float*  sim   = (float*)((char*)d_ws + FNORM_BYTES);
    float*  rloss = (float*)((char*)d_ws + FNORM_BYTES + SIM_BYTES);
    float*  rpos  = (float*)((char*)d_ws + FNORM_BYTES + SIM_BYTES + RL_BYTES);

    norm_bf16_kernel<<<dim3(BB * NP), 256, 0, stream>>>(feat, fnorm);
    simgemm_mfma<<<dim3(NP / 128, NP / 128, BB), 512, 0, stream>>>(fnorm, sim);
    rowloss_kernel<<<dim3(NN / 4, BB), 256, 0, stream>>>(sim, tgt, rloss, rpos);
    final_kernel<<<1, 256, 0, stream>>>(rloss, rpos, (float*)d_out);
}

// Round 4
// 123.577 us; speedup vs baseline: 3.5643x; 1.0591x over previous
//
#include <hip/hip_runtime.h>
#include <math.h>

// Problem constants (from reference setup_inputs)
#define BB 4
#define NN 1000
#define NP 1024          // padded N for MFMA tiles
#define CC 2048
#define TINV (1.0f / 0.07f)

// Workspace layout:
//   [0, 16 MB)   : normalized features, bf16, B*NP*CC (rows >= NN zeroed)
//   [+33.6 MB)   : sim partials, fp32, [2*BB][NP][NP]  (split-K=2; buffer
//                  index bz = 2*b + kz; rowloss adds the two halves)
//   then         : per-row loss sums  rloss[B*NP], pos counts rpos[B*NP]
// No atomics anywhere (R2: 8000 same-line device atomicAdds = 110 us).
// Split-K=2 (R4): 256 blocks was 1 block/CU -> no inter-block overlap to
// hide the barrier drain; 512 blocks gives 2 independent blocks/CU.
#define FNORM_BYTES ((size_t)BB * NP * CC * 2)
#define SIMP_BYTES  ((size_t)2 * BB * NP * NP * 4)
#define RL_BYTES    ((size_t)BB * NP * 4)

typedef __bf16 bf16x8 __attribute__((ext_vector_type(8)));
typedef float  f32x4  __attribute__((ext_vector_type(4)));

// ---------------------------------------------------------------------------
__device__ __forceinline__ void load_lds16(const void* g, void* l) {
    // async global->LDS, 16B/lane; LDS dest = wave-uniform base + lane*16
    __builtin_amdgcn_global_load_lds(
        (const __attribute__((address_space(1))) unsigned int*)g,
        (__attribute__((address_space(3))) unsigned int*)l, 16, 0, 0);
}

__device__ __forceinline__ float blk_sum(float v, volatile float* lds) {
    int lane = threadIdx.x & 63;
    int wid  = threadIdx.x >> 6;
#pragma unroll
    for (int off = 32; off; off >>= 1) v += __shfl_down(v, off);
    __syncthreads();
    if (lane == 0) lds[wid] = v;
    __syncthreads();
    return lds[0] + lds[1] + lds[2] + lds[3];
}

__device__ __forceinline__ float wave_sum(float v) {
#pragma unroll
    for (int off = 32; off; off >>= 1) v += __shfl_down(v, off);
    return __shfl(v, 0);
}

// ---------------------------------------------------------------------------
// K1: L2-normalize each row, output bf16 into padded [NP x CC] buffer.
// Rows >= NN are zero-filled (so the GEMM needs no bounds checks).
__global__ __launch_bounds__(256) void norm_bf16_kernel(const float* __restrict__ f,
                                                        __bf16* __restrict__ out) {
    __shared__ float lds[4];
    __shared__ float scale_s;
    const int blk = blockIdx.x;              // b*NP + padded row
    const int b = blk >> 10, r = blk & (NP - 1);
    __bf16* dst = out + ((size_t)b * NP + r) * CC;
    const int tid = threadIdx.x;

    if (r >= NN) {                           // zero pad rows: 2048 bf16 = 256 x 16B
        ((uint4*)dst)[tid] = make_uint4(0u, 0u, 0u, 0u);
        return;
    }
    const float* src = f + ((size_t)b * NN + r) * CC;

    float ss = 0.f;
#pragma unroll
    for (int h = 0; h < 2; ++h) {
        float4 v = ((const float4*)src)[tid + h * 256];
        ss += v.x * v.x + v.y * v.y + v.z * v.z + v.w * v.w;
    }
    float tot = blk_sum(ss, lds);
    if (tid == 0) scale_s = 1.0f / fmaxf(sqrtf(tot), 1e-12f);
    __syncthreads();
    const float sc = scale_s;

    float4 v0 = ((const float4*)src)[tid * 2];
    float4 v1 = ((const float4*)src)[tid * 2 + 1];
    bf16x8 o;
    o[0] = (__bf16)(v0.x * sc); o[1] = (__bf16)(v0.y * sc);
    o[2] = (__bf16)(v0.z * sc); o[3] = (__bf16)(v0.w * sc);
    o[4] = (__bf16)(v1.x * sc); o[5] = (__bf16)(v1.y * sc);
    o[6] = (__bf16)(v1.z * sc); o[7] = (__bf16)(v1.w * sc);
    *(bf16x8*)(dst + tid * 8) = o;
}

// ---------------------------------------------------------------------------
// K2: simp[2b+kz] = partial (fn[b] * fn[b]^T) * (1/T) over K-half kz.
// bf16 MFMA, 128x128 tile, BK=32, 512 threads (8 waves), wave = 64x32
// (4x2 grid of 16x16x32 MFMA). Staging via global_load_lds width=16.
// Split-K=2: grid.z = 2*BB -> 512 blocks = 2 blocks/CU, independent
// barriers per block hide each other's staging drain.
__global__ __launch_bounds__(512) void simgemm_mfma(const __bf16* __restrict__ fn,
                                                    float* __restrict__ simp) {
    __shared__ __bf16 As[128 * 32];
    __shared__ __bf16 Bs[128 * 32];

    const int bz = blockIdx.z;       // 0..2*BB-1
    const int b  = bz >> 1;
    const int kbeg = (bz & 1) * (CC / 2);
    const int tI = blockIdx.y * 128;
    const int tJ = blockIdx.x * 128;
    const __bf16* base = fn + (size_t)b * NP * CC;
    float* S = simp + (size_t)bz * NP * NP;

    const int tid  = threadIdx.x;
    const int wid  = tid >> 6;       // 0..7
    const int lane = tid & 63;
    const int wm   = wid >> 2;       // 0..1  (M quadrant, 64 rows)
    const int wn   = wid & 3;        // 0..3  (N quadrant, 32 cols)
    const int q    = lane >> 4;      // 0..3
    const int ln   = lane & 15;

    const int srow  = wid * 16 + (lane >> 2);       // 0..127
    const int selem = (lane & 3) * 8;               // bf16 elem offset in row
    const __bf16* gA = base + (size_t)(tI + srow) * CC + kbeg + selem;
    const __bf16* gB = base + (size_t)(tJ + srow) * CC + kbeg + selem;
    __bf16* lA = As + wid * 512;     // wave-uniform LDS base (lane*16B implicit)
    __bf16* lB = Bs + wid * 512;

    f32x4 acc[4][2] = {};

    for (int k0 = 0; k0 < CC / 2; k0 += 32) {
        load_lds16(gA + k0, lA);
        load_lds16(gB + k0, lB);
        __syncthreads();             // drains vmcnt(0): LDS tiles ready

        bf16x8 af[4], bf[2];
#pragma unroll
        for (int mt = 0; mt < 4; ++mt)
            af[mt] = *(const bf16x8*)&As[(wm * 64 + mt * 16 + ln) * 32 + q * 8];
#pragma unroll
        for (int nt = 0; nt < 2; ++nt)
            bf[nt] = *(const bf16x8*)&Bs[(wn * 32 + nt * 16 + ln) * 32 + q * 8];
#pragma unroll
        for (int mt = 0; mt < 4; ++mt)
#pragma unroll
            for (int nt = 0; nt < 2; ++nt)
                acc[mt][nt] = __builtin_amdgcn_mfma_f32_16x16x32_bf16(
                    af[mt], bf[nt], acc[mt][nt], 0, 0, 0);
        __syncthreads();             // all waves done reading before overwrite
    }

    // C/D layout (m89-verified): col = lane&15, row = (lane>>4)*4 + r
#pragma unroll
    for (int mt = 0; mt < 4; ++mt) {
#pragma unroll
        for (int nt = 0; nt < 2; ++nt) {
            const int col = tJ + wn * 32 + nt * 16 + ln;
#pragma unroll
            for (int r = 0; r < 4; ++r) {
                const int row = tI + wm * 64 + mt * 16 + q * 4 + r;
                S[(size_t)row * NP + col] = acc[mt][nt][r] * TINV;
            }
        }
    }
}

// ---------------------------------------------------------------------------
// K3: per-row masked reductions, one WAVE per row (4 rows/block).
// Row loss-mat sum = (N - p_i)*log(1+S_i) + sum_{pos j}[log(exp(s)+S_i) - s]
// Diagonal excluded by masking j==i (NOT by subtracting exp(sim_ii):
// exp(1/0.07)=1.6e6 vs S_i~1e3 would be catastrophic cancellation).
// Reads both split-K partial buffers and adds. NO atomics.
__global__ __launch_bounds__(256) void rowloss_kernel(const float* __restrict__ simp,
                                                      const int* __restrict__ tgt,
                                                      float* __restrict__ rloss,
                                                      float* __restrict__ rpos) {
    __shared__ int ts[NN];
    const int b = blockIdx.y;
    const int wid = threadIdx.x >> 6, lane = threadIdx.x & 63;
    const int* t = tgt + (size_t)b * NN;
    for (int j = threadIdx.x; j < NN; j += 256) ts[j] = t[j];
    __syncthreads();

    const int i = blockIdx.x * 4 + wid;            // grid.x = 250 -> i < 1000
    const float* r0 = simp + (size_t)(2 * b) * NP * NP + (size_t)i * NP;
    const float* r1 = r0 + (size_t)NP * NP;
    const int ti = ts[i];

    float sneg = 0.f, pcnt = 0.f;
    for (int g = lane; g < NN / 4; g += 64) {      // 250 float4 groups
        float4 a = ((const float4*)r0)[g];
        float4 c = ((const float4*)r1)[g];
        float4 v = make_float4(a.x + c.x, a.y + c.y, a.z + c.z, a.w + c.w);
        int4 tj = *(const int4*)&ts[g * 4];
        const int j = g * 4;
        if (j + 0 != i) { if (tj.x == ti) pcnt += 1.f; else sneg += __expf(v.x); }
        if (j + 1 != i) { if (tj.y == ti) pcnt += 1.f; else sneg += __expf(v.y); }
        if (j + 2 != i) { if (tj.z == ti) pcnt += 1.f; else sneg += __expf(v.z); }
        if (j + 3 != i) { if (tj.w == ti) pcnt += 1.f; else sneg += __expf(v.w); }
    }
    const float Sv = wave_sum(sneg);
    const float p  = wave_sum(pcnt);

    float term = 0.f;                               // second pass: rows are L2-hot
    for (int g = lane; g < NN / 4; g += 64) {
        float4 a = ((const float4*)r0)[g];
        float4 c = ((const float4*)r1)[g];
        float4 v = make_float4(a.x + c.x, a.y + c.y, a.z + c.z, a.w + c.w);
        int4 tj = *(const int4*)&ts[g * 4];
        const int j = g * 4;
        if (j + 0 != i && tj.x == ti) term += __logf(__expf(v.x) + Sv) - v.x;
        if (j + 1 != i && tj.y == ti) term += __logf(__expf(v.y) + Sv) - v.y;
        if (j + 2 != i && tj.z == ti) term += __logf(__expf(v.z) + Sv) - v.z;
        if (j + 3 != i && tj.w == ti) term += __logf(__expf(v.w) + Sv) - v.w;
    }
    const float tt = wave_sum(term);
    if (lane == 0) {
        rloss[b * NP + i] = tt + ((float)NN - p) * __logf(1.f + Sv);
        rpos [b * NP + i] = p;
    }
}

// ---------------------------------------------------------------------------
// K4: reduce per-row partials and combine exactly as the reference does.
__global__ __launch_bounds__(256) void final_kernel(const float* __restrict__ rloss,
                                                    const float* __restrict__ rpos,
                                                    float* __restrict__ out) {
    __shared__ float lds[4];
    float total = 0.f, np = 0.f;
    for (int b = 0; b < BB; ++b) {
        float l = 0.f, p = 0.f;
        for (int i = threadIdx.x; i < NN; i += 256) {
            l += rloss[b * NP + i];
            p += rpos [b * NP + i];
        }
        float ls = blk_sum(l, lds);
        float ps = blk_sum(p, lds);
        if (ps > 0.f) { total += ls / (ps + 1e-6f); np += 1.f; }
    }
    if (threadIdx.x == 0)
        out[0] = (np > 0.f) ? 0.1f * total / np : 0.1f * 0.1f;
}

// ---------------------------------------------------------------------------
extern "C" void kernel_launch(void* const* d_in, const int* in_sizes, int n_in,
                              void* d_out, int out_size, void* d_ws, size_t ws_size,
                              hipStream_t stream) {
    const float* feat = (const float*)d_in[0];
    const int*   tgt  = (const int*)d_in[1];
    __bf16* fnorm = (__bf16*)d_ws;
    float*  simp  = (float*)((char*)d_ws + FNORM_BYTES);
    float*  rloss = (float*)((char*)d_ws + FNORM_BYTES + SIMP_BYTES);
    float*  rpos  = (float*)((char*)d_ws + FNORM_BYTES + SIMP_BYTES + RL_BYTES);

    norm_bf16_kernel<<<dim3(BB * NP), 256, 0, stream>>>(feat, fnorm);
    simgemm_mfma<<<dim3(NP / 128, NP / 128, 2 * BB), 512, 0, stream>>>(fnorm, simp);
    rowloss_kernel<<<dim3(NN / 4, BB), 256, 0, stream>>>(simp, tgt, rloss, rpos);
    final_kernel<<<1, 256, 0, stream>>>(rloss, rpos, (float*)d_out);
}

// Round 5
// 120.459 us; speedup vs baseline: 3.6566x; 1.0259x over previous
//
#include <hip/hip_runtime.h>
#include <math.h>

// Problem constants (from reference setup_inputs)
#define BB 4
#define NN 1000
#define NP 1024          // padded N for MFMA tiles
#define CC 2048
#define TINV (1.0f / 0.07f)
#define BK 64

// Workspace layout:
//   [0, 16 MB)   : normalized features, bf16, B*NP*CC (rows >= NN zeroed)
//   [+33.6 MB)   : sim partials, fp32, [2*BB][NP][NP]  (split-K=2)
//   then         : per-row loss sums  rloss[B*NP], pos counts rpos[B*NP]
// No atomics anywhere (R2: 8000 same-line device atomicAdds = 110 us).
// Split-K=2 (R4): 512 blocks = 2 independent blocks/CU.
// R5: XOR-swizzled LDS (R4 frag reads were ~8-way bank-conflicted),
//     32x32x16 MFMA with 64x64 wave tiles (32 FLOP/LDS-byte vs 21.8), BK=64.
#define FNORM_BYTES ((size_t)BB * NP * CC * 2)
#define SIMP_BYTES  ((size_t)2 * BB * NP * NP * 4)
#define RL_BYTES    ((size_t)BB * NP * 4)

typedef __bf16 bf16x8 __attribute__((ext_vector_type(8)));
typedef float  f32x4  __attribute__((ext_vector_type(4)));
typedef float  f32x16 __attribute__((ext_vector_type(16)));

// ---------------------------------------------------------------------------
__device__ __forceinline__ void load_lds16(const void* g, void* l) {
    // async global->LDS, 16B/lane; LDS dest = wave-uniform base + lane*16
    __builtin_amdgcn_global_load_lds(
        (const __attribute__((address_space(1))) unsigned int*)g,
        (__attribute__((address_space(3))) unsigned int*)l, 16, 0, 0);
}

__device__ __forceinline__ float blk_sum(float v, volatile float* lds) {
    int lane = threadIdx.x & 63;
    int wid  = threadIdx.x >> 6;
#pragma unroll
    for (int off = 32; off; off >>= 1) v += __shfl_down(v, off);
    __syncthreads();
    if (lane == 0) lds[wid] = v;
    __syncthreads();
    return lds[0] + lds[1] + lds[2] + lds[3];
}

__device__ __forceinline__ float wave_sum(float v) {
#pragma unroll
    for (int off = 32; off; off >>= 1) v += __shfl_down(v, off);
    return __shfl(v, 0);
}

// ---------------------------------------------------------------------------
// K1: L2-normalize each row, output bf16 into padded [NP x CC] buffer.
// Rows >= NN are zero-filled (so the GEMM needs no bounds checks).
__global__ __launch_bounds__(256) void norm_bf16_kernel(const float* __restrict__ f,
                                                        __bf16* __restrict__ out) {
    __shared__ float lds[4];
    __shared__ float scale_s;
    const int blk = blockIdx.x;              // b*NP + padded row
    const int b = blk >> 10, r = blk & (NP - 1);
    __bf16* dst = out + ((size_t)b * NP + r) * CC;
    const int tid = threadIdx.x;

    if (r >= NN) {                           // zero pad rows: 2048 bf16 = 256 x 16B
        ((uint4*)dst)[tid] = make_uint4(0u, 0u, 0u, 0u);
        return;
    }
    const float* src = f + ((size_t)b * NN + r) * CC;

    float ss = 0.f;
#pragma unroll
    for (int h = 0; h < 2; ++h) {
        float4 v = ((const float4*)src)[tid + h * 256];
        ss += v.x * v.x + v.y * v.y + v.z * v.z + v.w * v.w;
    }
    float tot = blk_sum(ss, lds);
    if (tid == 0) scale_s = 1.0f / fmaxf(sqrtf(tot), 1e-12f);
    __syncthreads();
    const float sc = scale_s;

    float4 v0 = ((const float4*)src)[tid * 2];
    float4 v1 = ((const float4*)src)[tid * 2 + 1];
    bf16x8 o;
    o[0] = (__bf16)(v0.x * sc); o[1] = (__bf16)(v0.y * sc);
    o[2] = (__bf16)(v0.z * sc); o[3] = (__bf16)(v0.w * sc);
    o[4] = (__bf16)(v1.x * sc); o[5] = (__bf16)(v1.y * sc);
    o[6] = (__bf16)(v1.z * sc); o[7] = (__bf16)(v1.w * sc);
    *(bf16x8*)(dst + tid * 8) = o;
}

// ---------------------------------------------------------------------------
// K2: simp[2b+kz] = partial (fn[b] * fn[b]^T) * (1/T) over K-half kz.
// 256 threads (4 waves), tile 128x128, BK=64; wave = 64x64 via 2x2 of
// v_mfma_f32_32x32x16_bf16. LDS tiles [128 rows][64 K] bf16, with the 16B
// chunk slot XOR-swizzled: (row, chunk c) lives at slot (c ^ (row&7)).
// Swizzle is applied on the GLOBAL side of global_load_lds (lane l fetches
// chunk (l&7)^((l>>3)&7) of its row -> same 128B segment, coalescing kept),
// so frag ds_read_b128 hit all 32 banks uniformly (R4 was ~8-way conflicted).
__global__ __launch_bounds__(256) void simgemm_mfma(const __bf16* __restrict__ fn,
                                                    float* __restrict__ simp) {
    __shared__ __bf16 As[128 * BK];   // 16 KB
    __shared__ __bf16 Bs[128 * BK];

    const int bz = blockIdx.z;        // 0..2*BB-1
    const int b  = bz >> 1;
    const int kbeg = (bz & 1) * (CC / 2);
    const int tI = blockIdx.y * 128;
    const int tJ = blockIdx.x * 128;
    const __bf16* base = fn + (size_t)b * NP * CC;
    float* S = simp + (size_t)bz * NP * NP;

    const int tid  = threadIdx.x;
    const int wid  = tid >> 6;        // 0..3
    const int lane = tid & 63;
    const int wm   = wid >> 1;        // 0..1  (M half, 64 rows)
    const int wn   = wid & 1;         // 0..1  (N half, 64 cols)
    const int ln32 = lane & 31;
    const int kh   = lane >> 5;       // k-half within frag (0..1)
    const int sw   = ln32 & 7;        // frag-read swizzle key

    // staging: round r covers rows r*32 + (tid>>3); lane carries swizzled chunk
    const int srow   = tid >> 3;                    // 0..31
    const int schunk = (tid & 7) ^ (srow & 7);      // XOR swizzle, global side
    const __bf16* gA = base + (size_t)(tI + srow) * CC + kbeg + schunk * 8;
    const __bf16* gB = base + (size_t)(tJ + srow) * CC + kbeg + schunk * 8;
    __bf16* lA = As + (size_t)wid * 8 * BK;         // wave-uniform LDS base
    __bf16* lB = Bs + (size_t)wid * 8 * BK;

    f32x16 acc[2][2] = {};

    for (int k0 = 0; k0 < CC / 2; k0 += BK) {
#pragma unroll
        for (int r = 0; r < 4; ++r)
            load_lds16(gA + k0 + (size_t)r * 32 * CC, lA + r * 32 * BK);
#pragma unroll
        for (int r = 0; r < 4; ++r)
            load_lds16(gB + k0 + (size_t)r * 32 * CC, lB + r * 32 * BK);
        __syncthreads();              // drains vmcnt(0): LDS tiles ready

#pragma unroll
        for (int kc = 0; kc < 4; ++kc) {
            const int c = kc * 2 + kh;              // 16B chunk index 0..7
            const int co = (c ^ sw) * 8;            // swizzled elem offset
            bf16x8 a0 = *(const bf16x8*)&As[(wm * 64      + ln32) * BK + co];
            bf16x8 a1 = *(const bf16x8*)&As[(wm * 64 + 32 + ln32) * BK + co];
            bf16x8 b0 = *(const bf16x8*)&Bs[(wn * 64      + ln32) * BK + co];
            bf16x8 b1 = *(const bf16x8*)&Bs[(wn * 64 + 32 + ln32) * BK + co];
            acc[0][0] = __builtin_amdgcn_mfma_f32_32x32x16_bf16(a0, b0, acc[0][0], 0, 0, 0);
            acc[0][1] = __builtin_amdgcn_mfma_f32_32x32x16_bf16(a0, b1, acc[0][1], 0, 0, 0);
            acc[1][0] = __builtin_amdgcn_mfma_f32_32x32x16_bf16(a1, b0, acc[1][0], 0, 0, 0);
            acc[1][1] = __builtin_amdgcn_mfma_f32_32x32x16_bf16(a1, b1, acc[1][1], 0, 0, 0);
        }
        __syncthreads();              // all waves done reading before overwrite
    }

    // C/D layout (m74/m101-verified): col = lane&31,
    // row = (reg&3) + 8*(reg>>2) + 4*(lane>>5)
#pragma unroll
    for (int at = 0; at < 2; ++at) {
#pragma unroll
        for (int bt = 0; bt < 2; ++bt) {
            const int col = tJ + wn * 64 + bt * 32 + ln32;
#pragma unroll
            for (int r = 0; r < 16; ++r) {
                const int row = tI + wm * 64 + at * 32 + (r & 3) + 8 * (r >> 2) + 4 * kh;
                S[(size_t)row * NP + col] = acc[at][bt][r] * TINV;
            }
        }
    }
}

// ---------------------------------------------------------------------------
// K3: per-row masked reductions, one WAVE per row (4 rows/block).
// Row loss-mat sum = (N - p_i)*log(1+S_i) + sum_{pos j}[log(exp(s)+S_i) - s]
// Diagonal excluded by masking j==i (NOT by subtracting exp(sim_ii):
// exp(1/0.07)=1.6e6 vs S_i~1e3 would be catastrophic cancellation).
// Split-K partials are summed ONCE and cached in LDS; pass 2 reads LDS
// (R4 re-read 33.6 MB from global). NO atomics.
__global__ __launch_bounds__(256) void rowloss_kernel(const float* __restrict__ simp,
                                                      const int* __restrict__ tgt,
                                                      float* __restrict__ rloss,
                                                      float* __restrict__ rpos) {
    __shared__ int ts[NN];
    __shared__ float rowv[4][NP];                  // 16 KB row cache
    const int b = blockIdx.y;
    const int wid = threadIdx.x >> 6, lane = threadIdx.x & 63;
    const int* t = tgt + (size_t)b * NN;
    for (int j = threadIdx.x; j < NN; j += 256) ts[j] = t[j];
    __syncthreads();

    const int i = blockIdx.x * 4 + wid;            // grid.x = 250 -> i < 1000
    const float* r0 = simp + (size_t)(2 * b) * NP * NP + (size_t)i * NP;
    const float* r1 = r0 + (size_t)NP * NP;
    const int ti = ts[i];

    float sneg = 0.f, pcnt = 0.f;
    for (int g = lane; g < NN / 4; g += 64) {      // 250 float4 groups
        float4 a = ((const float4*)r0)[g];
        float4 c = ((const float4*)r1)[g];
        float4 v = make_float4(a.x + c.x, a.y + c.y, a.z + c.z, a.w + c.w);
        *(float4*)&rowv[wid][g * 4] = v;           // cache for pass 2
        int4 tj = *(const int4*)&ts[g * 4];
        const int j = g * 4;
        if (j + 0 != i) { if (tj.x == ti) pcnt += 1.f; else sneg += __expf(v.x); }
        if (j + 1 != i) { if (tj.y == ti) pcnt += 1.f; else sneg += __expf(v.y); }
        if (j + 2 != i) { if (tj.z == ti) pcnt += 1.f; else sneg += __expf(v.z); }
        if (j + 3 != i) { if (tj.w == ti) pcnt += 1.f; else sneg += __expf(v.w); }
    }
    const float Sv = wave_sum(sneg);
    const float p  = wave_sum(pcnt);

    float term = 0.f;                              // pass 2: LDS only (wave-private)
    for (int g = lane; g < NN / 4; g += 64) {
        float4 v = *(const float4*)&rowv[wid][g * 4];
        int4 tj = *(const int4*)&ts[g * 4];
        const int j = g * 4;
        if (j + 0 != i && tj.x == ti) term += __logf(__expf(v.x) + Sv) - v.x;
        if (j + 1 != i && tj.y == ti) term += __logf(__expf(v.y) + Sv) - v.y;
        if (j + 2 != i && tj.z == ti) term += __logf(__expf(v.z) + Sv) - v.z;
        if (j + 3 != i && tj.w == ti) term += __logf(__expf(v.w) + Sv) - v.w;
    }
    const float tt = wave_sum(term);
    if (lane == 0) {
        rloss[b * NP + i] = tt + ((float)NN - p) * __logf(1.f + Sv);
        rpos [b * NP + i] = p;
    }
}

// ---------------------------------------------------------------------------
// K4: reduce per-row partials and combine exactly as the reference does.
__global__ __launch_bounds__(256) void final_kernel(const float* __restrict__ rloss,
                                                    const float* __restrict__ rpos,
                                                    float* __restrict__ out) {
    __shared__ float lds[4];
    float total = 0.f, np = 0.f;
    for (int b = 0; b < BB; ++b) {
        float l = 0.f, p = 0.f;
        for (int i = threadIdx.x; i < NN; i += 256) {
            l += rloss[b * NP + i];
            p += rpos [b * NP + i];
        }
        float ls = blk_sum(l, lds);
        float ps = blk_sum(p, lds);
        if (ps > 0.f) { total += ls / (ps + 1e-6f); np += 1.f; }
    }
    if (threadIdx.x == 0)
        out[0] = (np > 0.f) ? 0.1f * total / np : 0.1f * 0.1f;
}

// ---------------------------------------------------------------------------
extern "C" void kernel_launch(void* const* d_in, const int* in_sizes, int n_in,
                              void* d_out, int out_size, void* d_ws, size_t ws_size,
                              hipStream_t stream) {
    const float* feat = (const float*)d_in[0];
    const int*   tgt  = (const int*)d_in[1];
    __bf16* fnorm = (__bf16*)d_ws;
    float*  simp  = (float*)((char*)d_ws + FNORM_BYTES);
    float*  rloss = (float*)((char*)d_ws + FNORM_BYTES + SIMP_BYTES);
    float*  rpos  = (float*)((char*)d_ws + FNORM_BYTES + SIMP_BYTES + RL_BYTES);

    norm_bf16_kernel<<<dim3(BB * NP), 256, 0, stream>>>(feat, fnorm);
    simgemm_mfma<<<dim3(NP / 128, NP / 128, 2 * BB), 256, 0, stream>>>(fnorm, simp);
    rowloss_kernel<<<dim3(NN / 4, BB), 256, 0, stream>>>(simp, tgt, rloss, rpos);
    final_kernel<<<1, 256, 0, stream>>>(rloss, rpos, (float*)d_out);
}